// Round 4
// baseline (114.528 us; speedup 1.0000x reference)
//
#include <hip/hip_runtime.h>
#include <math.h>

// ---------------------------------------------------------------------------
// LorentzSelfAttention — MI355X
//
// Degenerate-clamp simplification (verified analytically, passed R1-R3):
//   u_agg_i = C*(W_i + S_i*Q_i),  W_i = sum_j attn*dist*V_j,
//                                 S_i = sum_j attn*dist*alpha_ij
//   Y_i = mink_normalize(Q_i + u_agg_i), |time|
//   Ztan_i = dist0*C * (2*Y0, Ys),  dist0 = acosh(max(Y0,1+eps))
//
// R4: attn restructured for occupancy: 8 rows/block, grid 1024 (4 blk/CU,
// 8 waves/SIMD via __launch_bounds__(512,8)); Q via LDS broadcast (no scalar
// pipe); chunked K/V register tiles (VGPR<=64, no spills); wave-centric P4
// with float4 reads. QKV/out GEMMs unchanged from R3.
// ---------------------------------------------------------------------------

namespace {

constexpr int Tq   = 512;
constexpr int Hq   = 8;
constexpr int QS   = 36;          // padded Q row stride

#define EPSF  1e-6f
#define CINV  3.16227766e7f       // 1/sqrt(1e-15)

__device__ __forceinline__ float facosh(float x) {
    // caller guarantees x >= 1+1e-6
    return __logf(x + __builtin_amdgcn_sqrtf(fmaf(x, x, -1.0f)));
}

// ---------------- Kernel 1: QKV GEMM + fused FL lift (as R3) ---------------
__global__ __launch_bounds__(256) void gemm_qkv_fl_kernel(
    const float* __restrict__ x,
    const float* __restrict__ Wq, const float* __restrict__ bq,
    const float* __restrict__ Wk, const float* __restrict__ bk,
    const float* __restrict__ Wv, const float* __restrict__ bv,
    float* __restrict__ Q, float* __restrict__ K, float* __restrict__ V)
{
    __shared__ float AsT[16][68];     // k-major
    __shared__ float BsT[16][68];
    __shared__ float sT[64][65];      // epilogue z-tile

    const int n0 = blockIdx.x * 64;
    const int m0 = blockIdx.y * 64;
    const int t  = threadIdx.x;
    const int tx = t & 15, ty = t >> 4;
    const int lr = t >> 2;
    const int lc = (t & 3) * 4;

    float acc[4][4];
    #pragma unroll
    for (int r = 0; r < 4; ++r)
        #pragma unroll
        for (int c = 0; c < 4; ++c) acc[r][c] = 0.f;

    const int og = n0 + lr;
    const float* Wsel = (og < 256) ? Wq : (og < 512 ? Wk : Wv);
    const int orow = og & 255;

    for (int k0 = 0; k0 < 512; k0 += 16) {
        const float4 av = *reinterpret_cast<const float4*>(&x[(m0 + lr) * 512 + k0 + lc]);
        AsT[lc + 0][lr] = av.x; AsT[lc + 1][lr] = av.y;
        AsT[lc + 2][lr] = av.z; AsT[lc + 3][lr] = av.w;
        const float4 bw = *reinterpret_cast<const float4*>(&Wsel[orow * 512 + k0 + lc]);
        BsT[lc + 0][lr] = bw.x; BsT[lc + 1][lr] = bw.y;
        BsT[lc + 2][lr] = bw.z; BsT[lc + 3][lr] = bw.w;
        __syncthreads();
        #pragma unroll
        for (int kk = 0; kk < 16; ++kk) {
            const float4 a4 = *reinterpret_cast<const float4*>(&AsT[kk][ty * 4]);
            const float4 b4 = *reinterpret_cast<const float4*>(&BsT[kk][tx * 4]);
            const float ar[4] = {a4.x, a4.y, a4.z, a4.w};
            const float br[4] = {b4.x, b4.y, b4.z, b4.w};
            #pragma unroll
            for (int r = 0; r < 4; ++r)
                #pragma unroll
                for (int c = 0; c < 4; ++c) acc[r][c] = fmaf(ar[r], br[c], acc[r][c]);
        }
        __syncthreads();
    }

    #pragma unroll
    for (int c = 0; c < 4; ++c) {
        const int o = n0 + tx * 4 + c;
        const float* bsel = (o < 256) ? bq : (o < 512 ? bk : bv);
        const float bias = bsel[o & 255];
        #pragma unroll
        for (int r = 0; r < 4; ++r)
            sT[ty * 4 + r][tx * 4 + c] = acc[r][c] + bias;
    }
    __syncthreads();

    if (t < 128) {
        const int m = t >> 1, half = t & 1;
        const int row = m0 + m;
        const int b = row >> 9, tt = row & 511;
        const int which = n0 >> 8;
        const int h = ((n0 & 255) >> 5) + half;
        const int bh = b * Hq + h;

        float zv[32];
        float s2 = 0.f;
        #pragma unroll
        for (int k = 0; k < 32; ++k) { zv[k] = sT[m][half * 32 + k]; s2 = fmaf(zv[k], zv[k], s2); }
        const float rr = __builtin_amdgcn_sqrtf(s2);
        const float rs = fminf(fmaxf(rr, 1e-12f), 18.0f);
        const float e  = __expf(rs);
        const float ei = __builtin_amdgcn_rcpf(e);
        const float ch = 0.5f * (e + ei);
        float sc = 0.5f * (e - ei) / rs;
        if (rs < 1e-3f) sc = fmaf(rs * rs, 1.0f / 6.0f, 1.0f);
        float y0 = ch;
        float ys[32];
        float mink = -y0 * y0;
        #pragma unroll
        for (int k = 0; k < 32; ++k) { ys[k] = sc * zv[k]; mink = fmaf(ys[k], ys[k], mink); }
        const float inv = __builtin_amdgcn_rsqf(fmaxf(fabsf(mink), 1e-15f));
        y0 = fabsf(y0 * inv);

        if (which == 0) {
            float* qp = Q + (bh * Tq + tt) * QS;
            #pragma unroll
            for (int k = 0; k < 32; ++k) qp[k] = ys[k] * inv;
            qp[32] = y0;
        } else {
            float* p = ((which == 1) ? K : V) + bh * 33 * Tq + tt;
            p[0] = y0;
            #pragma unroll
            for (int k = 0; k < 32; ++k) p[(k + 1) * Tq] = ys[k] * inv;
        }
    }
}

// ---------------- Kernel 2: attention + Karcher step + origin log ----------
// 512 threads, 8 rows/block, grid (64, 16) = 1024 blocks -> 4 blocks/CU,
// 8 waves/SIMD. Q in LDS (broadcast reads); K/V chunked register tiles.
__global__ __launch_bounds__(512, 8) void attn_kernel(
    const float* __restrict__ Q, const float* __restrict__ K,
    const float* __restrict__ V, float* __restrict__ Ztan)
{
    __shared__ float sQ[8][36];       // [0..31]=spatial, [32]=time
    __shared__ float sBig[8 * 512];   // scores -> w; P4 partials alias
    __shared__ float sM[8], sInv[8];
    __shared__ float sSp[8][8];
    __shared__ float sW[8][33];
    __shared__ float sSum[8];

    float (*sS)[512] = reinterpret_cast<float(*)[512]>(sBig);
    float (*part)[2][8][20] = reinterpret_cast<float(*)[2][8][20]>(sBig);

    const int bh = blockIdx.y;
    const int i0 = blockIdx.x * 8;
    const int t  = threadIdx.x;       // 0..511
    const int lane = t & 63, wv = t >> 6;

    const float* Qb = Q + (bh * Tq + i0) * QS;
    const float* Kb = K + bh * 33 * Tq;
    const float* Vb = V + bh * 33 * Tq;

    if (t < 8 * QS) sQ[t / QS][t % QS] = Qb[t];
    __syncthreads();

    // ---- P1: scores = -acosh(ip)^2, thread = column j -----------------
    {
        const int j = t;
        float accd[8];
        #pragma unroll
        for (int i = 0; i < 8; ++i) accd[i] = 0.f;
        #pragma unroll 1
        for (int chunk = 0; chunk < 2; ++chunk) {
            float ks[16];
            #pragma unroll
            for (int k = 0; k < 16; ++k) ks[k] = Kb[(chunk * 16 + k + 1) * Tq + j];
            #pragma unroll 2
            for (int i = 0; i < 8; ++i) {
                float d0 = accd[i], d1 = 0.f, d2 = 0.f, d3 = 0.f;
                #pragma unroll
                for (int c = 0; c < 4; ++c) {
                    const float4 q4 = *reinterpret_cast<const float4*>(&sQ[i][chunk * 16 + c * 4]);
                    d0 = fmaf(q4.x, ks[c * 4 + 0], d0);
                    d1 = fmaf(q4.y, ks[c * 4 + 1], d1);
                    d2 = fmaf(q4.z, ks[c * 4 + 2], d2);
                    d3 = fmaf(q4.w, ks[c * 4 + 3], d3);
                }
                accd[i] = (d0 + d1) + (d2 + d3);
            }
        }
        const float k0v = Kb[j];
        #pragma unroll
        for (int i = 0; i < 8; ++i) {
            const float ip = sQ[i][32] * k0v - accd[i];
            const float d  = facosh(fmaxf(ip, 1.0f + EPSF));
            sS[i][j] = -d * d;
        }
    }
    __syncthreads();

    // ---- P2: softmax stats, wave wv handles row wv --------------------
    {
        const int i = wv;
        float m = -1e30f;
        #pragma unroll
        for (int q = 0; q < 8; ++q) m = fmaxf(m, sS[i][lane + 64 * q]);
        #pragma unroll
        for (int off = 32; off > 0; off >>= 1) m = fmaxf(m, __shfl_xor(m, off, 64));
        float sum = 0.f;
        #pragma unroll
        for (int q = 0; q < 8; ++q) sum += __expf(sS[i][lane + 64 * q] - m);
        #pragma unroll
        for (int off = 32; off > 0; off >>= 1) sum += __shfl_xor(sum, off, 64);
        if (lane == 0) { sM[i] = m; sInv[i] = __builtin_amdgcn_rcpf(sum); }
    }
    __syncthreads();

    // ---- P3: w_ij = attn*dist(alpha); S partials; overwrite sS with w -
    {
        const int j = t;
        float accd[8];
        #pragma unroll
        for (int i = 0; i < 8; ++i) accd[i] = 0.f;
        #pragma unroll 1
        for (int chunk = 0; chunk < 2; ++chunk) {
            float vs[16];
            #pragma unroll
            for (int k = 0; k < 16; ++k) vs[k] = Vb[(chunk * 16 + k + 1) * Tq + j];
            #pragma unroll 2
            for (int i = 0; i < 8; ++i) {
                float d0 = accd[i], d1 = 0.f, d2 = 0.f, d3 = 0.f;
                #pragma unroll
                for (int c = 0; c < 4; ++c) {
                    const float4 q4 = *reinterpret_cast<const float4*>(&sQ[i][chunk * 16 + c * 4]);
                    d0 = fmaf(q4.x, vs[c * 4 + 0], d0);
                    d1 = fmaf(q4.y, vs[c * 4 + 1], d1);
                    d2 = fmaf(q4.z, vs[c * 4 + 2], d2);
                    d3 = fmaf(q4.w, vs[c * 4 + 3], d3);
                }
                accd[i] = (d0 + d1) + (d2 + d3);
            }
        }
        const float v0 = Vb[j];
        float sp[8];
        #pragma unroll
        for (int i = 0; i < 8; ++i) {
            const float al = fmaxf(sQ[i][32] * v0 - accd[i], 1.0f + EPSF);
            const float dd = facosh(al);
            const float aij = __expf(sS[i][j] - sM[i]) * sInv[i];
            const float w = aij * dd;
            sS[i][j] = w;
            sp[i] = w * al;
        }
        #pragma unroll
        for (int i = 0; i < 8; ++i) {
            float v = sp[i];
            #pragma unroll
            for (int off = 32; off > 0; off >>= 1) v += __shfl_xor(v, off, 64);
            if (lane == 0) sSp[i][wv] = v;
        }
    }
    __syncthreads();

    // ---- P4: W[i][a] = sum_j w_ij * V[a][j] ---------------------------
    // wave wv: a-columns wv*4..wv*4+4 (5 wide; waves 0-6 write 4, wave 7
    // writes 5). half-wave hw: rows hw*4..hw*4+3. lane jl covers j.
    {
        const int jl = lane & 31, hw = lane >> 5;
        const int abase = wv * 4;         // max 28; +4 = 32 <= 32, in range
        const int ibase = hw * 4;
        float acc[4][5];
        #pragma unroll
        for (int il = 0; il < 4; ++il)
            #pragma unroll
            for (int al = 0; al < 5; ++al) acc[il][al] = 0.f;

        #pragma unroll 1
        for (int it = 0; it < 4; ++it) {
            const int jb = it * 128 + jl * 4;
            float4 v4[5];
            #pragma unroll
            for (int al = 0; al < 5; ++al)
                v4[al] = *reinterpret_cast<const float4*>(&Vb[(abase + al) * Tq + jb]);
            #pragma unroll
            for (int il = 0; il < 4; ++il) {
                const float4 w4 = *reinterpret_cast<const float4*>(&sS[ibase + il][jb]);
                #pragma unroll
                for (int al = 0; al < 5; ++al) {
                    float s = fmaf(w4.x, v4[al].x, acc[il][al]);
                    s = fmaf(w4.y, v4[al].y, s);
                    s = fmaf(w4.z, v4[al].z, s);
                    acc[il][al] = fmaf(w4.w, v4[al].w, s);
                }
            }
        }
        #pragma unroll
        for (int il = 0; il < 4; ++il)
            #pragma unroll
            for (int al = 0; al < 5; ++al) {
                float v = acc[il][al];
                v += __shfl_xor(v, 1, 64);
                v += __shfl_xor(v, 2, 64);
                acc[il][al] = v;
            }
        __syncthreads();   // all sS reads done before part overwrites
        if ((jl & 3) == 0) {
            const int sub = jl >> 2;
            #pragma unroll
            for (int il = 0; il < 4; ++il)
                #pragma unroll
                for (int al = 0; al < 5; ++al)
                    part[wv][hw][sub][il * 5 + al] = acc[il][al];
        }
    }
    __syncthreads();

    // ---- stage 2: fold 8 partials per (i,a); reduce S -----------------
    if (t < 8 * 33) {
        const int i = t / 33, a = t - i * 33;
        int wv2, al;
        if (a < 28) { wv2 = a >> 2; al = a & 3; } else { wv2 = 7; al = a - 28; }
        const int hw2 = i >> 2, il = i & 3;
        float s = 0.f;
        #pragma unroll
        for (int sub = 0; sub < 8; ++sub) s += part[wv2][hw2][sub][il * 5 + al];
        sW[i][a] = s;
    }
    if (t < 8) {
        float s = 0.f;
        #pragma unroll
        for (int w = 0; w < 8; ++w) s += sSp[t][w];
        sSum[t] = s;
    }
    __syncthreads();

    // ---- P5: degenerate exp_map + project + origin log-map ------------
    if (t < 8) {
        const int i = t;
        const float S  = sSum[i];
        const float q0 = sQ[i][32];
        const float y0 = fmaf(CINV, fmaf(S, q0, sW[i][0]), q0);
        float mink = -y0 * y0;
        float yv[32];
        #pragma unroll
        for (int a = 1; a < 33; ++a) {
            const float qa = sQ[i][a - 1];
            const float ya = fmaf(CINV, fmaf(S, qa, sW[i][a]), qa);
            yv[a - 1] = ya;
            mink = fmaf(ya, ya, mink);
        }
        const float inv = __builtin_amdgcn_rsqf(fmaxf(fabsf(mink), 1e-15f));
        const float Y0 = fabsf(y0 * inv);
        const float dist0 = facosh(fmaxf(Y0, 1.0f + EPSF));
        const float coef = dist0 * CINV;
        const int b = bh >> 3, h = bh & 7;
        float* zp = Ztan + ((b * Tq + (i0 + i)) * 264) + h * 33;
        zp[0] = coef * (2.0f * Y0);
        #pragma unroll
        for (int a = 1; a < 33; ++a) zp[a] = coef * (yv[a - 1] * inv);
    }
}

// ---------------- Kernel 3: Z = Ztan(1024x264) @ Wo^T + bo (as R3) ---------
__global__ __launch_bounds__(256) void out_gemm_kernel(
    const float* __restrict__ Ztan, const float* __restrict__ Wo,
    const float* __restrict__ bo, float* __restrict__ out)
{
    __shared__ float AsT[8][68];
    __shared__ float BsT[8][68];
    const int n0 = blockIdx.x * 64;
    const int m0 = blockIdx.y * 64;
    const int t  = threadIdx.x;
    const int tx = t & 15, ty = t >> 4;
    const int lr = t >> 2;
    const int lc = (t & 3) * 2;

    float acc[4][4];
    #pragma unroll
    for (int r = 0; r < 4; ++r)
        #pragma unroll
        for (int c = 0; c < 4; ++c) acc[r][c] = 0.f;

    for (int k0 = 0; k0 < 264; k0 += 8) {
        const float2 av = *reinterpret_cast<const float2*>(&Ztan[(m0 + lr) * 264 + k0 + lc]);
        AsT[lc][lr] = av.x; AsT[lc + 1][lr] = av.y;
        const float2 bw = *reinterpret_cast<const float2*>(&Wo[(n0 + lr) * 264 + k0 + lc]);
        BsT[lc][lr] = bw.x; BsT[lc + 1][lr] = bw.y;
        __syncthreads();
        #pragma unroll
        for (int kk = 0; kk < 8; ++kk) {
            const float4 a4 = *reinterpret_cast<const float4*>(&AsT[kk][ty * 4]);
            const float4 b4 = *reinterpret_cast<const float4*>(&BsT[kk][tx * 4]);
            const float ar[4] = {a4.x, a4.y, a4.z, a4.w};
            const float br[4] = {b4.x, b4.y, b4.z, b4.w};
            #pragma unroll
            for (int r = 0; r < 4; ++r)
                #pragma unroll
                for (int c = 0; c < 4; ++c) acc[r][c] = fmaf(ar[r], br[c], acc[r][c]);
        }
        __syncthreads();
    }
    #pragma unroll
    for (int c = 0; c < 4; ++c) {
        const int o = n0 + tx * 4 + c;
        const float bias = bo[o];
        #pragma unroll
        for (int r = 0; r < 4; ++r)
            out[(m0 + ty * 4 + r) * 512 + o] = acc[r][c] + bias;
    }
}

} // namespace

// ---------------------------------------------------------------------------
extern "C" void kernel_launch(void* const* d_in, const int* in_sizes, int n_in,
                              void* d_out, int out_size, void* d_ws, size_t ws_size,
                              hipStream_t stream)
{
    const float* x  = (const float*)d_in[0];
    const float* Wq = (const float*)d_in[1];
    const float* bq = (const float*)d_in[2];
    const float* Wk = (const float*)d_in[3];
    const float* bk = (const float*)d_in[4];
    const float* Wv = (const float*)d_in[5];
    const float* bv = (const float*)d_in[6];
    const float* Wo = (const float*)d_in[7];
    const float* bo = (const float*)d_in[8];
    float* out = (float*)d_out;

    float* ws   = (float*)d_ws;
    float* Qw   = ws;                        // 16*512*36 = 294912
    float* Kw   = ws + 294912;               // 16*33*512 + pad = 272384
    float* Vw   = ws + 294912 + 272384;
    float* Zt   = ws + 294912 + 2 * 272384;  // 1024*264 = 270336

    gemm_qkv_fl_kernel<<<dim3(12, 16), 256, 0, stream>>>(x, Wq, bq, Wk, bk, Wv, bv,
                                                         Qw, Kw, Vw);
    attn_kernel<<<dim3(64, 16), 512, 0, stream>>>(Qw, Kw, Vw, Zt);
    out_gemm_kernel<<<dim3(8, 16), 256, 0, stream>>>(Zt, Wo, bo, out);
}

// Round 6
// 86.385 us; speedup vs baseline: 1.3258x; 1.3258x over previous
//
#include <hip/hip_runtime.h>
#include <math.h>

// ---------------------------------------------------------------------------
// LorentzSelfAttention — MI355X
//
// Degenerate-clamp simplification (verified analytically, passed R1-R4):
//   u_agg_i = C*(W_i + S_i*Q_i),  W_i = sum_j attn*dist*V_j,
//                                 S_i = sum_j attn*dist*alpha_ij
//   Y_i = mink_normalize(Q_i + u_agg_i), |time|
//   Ztan_i = dist0*C * (2*Y0, Ys),  dist0 = acosh(max(Y0,1+eps))
//
// R6 = R5 + fix: Q-tile LDS load was `if (t < 288)` with only 256 threads
// (rows 7 cols 4..35 uninitialized -> absmax 3.5e8). Now a strided loop.
// R5 design: 2-phase attn, no-max softmax (diagonal term => sum_e >= 1,
// scores in [-80,0], no f32 underflow), unnormalized p = e*dd, single
// normalization in epilogue. 256 thr, 8 rows/block, no min-waves clamp.
// ---------------------------------------------------------------------------

namespace {

constexpr int Tq   = 512;
constexpr int Hq   = 8;
constexpr int QS   = 36;          // padded Q row stride

#define EPSF  1e-6f
#define CINV  3.16227766e7f       // 1/sqrt(1e-15)

__device__ __forceinline__ float facosh(float x) {
    // caller guarantees x >= 1+1e-6
    return __logf(x + __builtin_amdgcn_sqrtf(fmaf(x, x, -1.0f)));
}

// ---------------- Kernel 1: QKV GEMM + fused FL lift (as R3) ---------------
__global__ __launch_bounds__(256) void gemm_qkv_fl_kernel(
    const float* __restrict__ x,
    const float* __restrict__ Wq, const float* __restrict__ bq,
    const float* __restrict__ Wk, const float* __restrict__ bk,
    const float* __restrict__ Wv, const float* __restrict__ bv,
    float* __restrict__ Q, float* __restrict__ K, float* __restrict__ V)
{
    __shared__ float AsT[16][68];     // k-major
    __shared__ float BsT[16][68];
    __shared__ float sT[64][65];      // epilogue z-tile

    const int n0 = blockIdx.x * 64;
    const int m0 = blockIdx.y * 64;
    const int t  = threadIdx.x;
    const int tx = t & 15, ty = t >> 4;
    const int lr = t >> 2;
    const int lc = (t & 3) * 4;

    float acc[4][4];
    #pragma unroll
    for (int r = 0; r < 4; ++r)
        #pragma unroll
        for (int c = 0; c < 4; ++c) acc[r][c] = 0.f;

    const int og = n0 + lr;
    const float* Wsel = (og < 256) ? Wq : (og < 512 ? Wk : Wv);
    const int orow = og & 255;

    for (int k0 = 0; k0 < 512; k0 += 16) {
        const float4 av = *reinterpret_cast<const float4*>(&x[(m0 + lr) * 512 + k0 + lc]);
        AsT[lc + 0][lr] = av.x; AsT[lc + 1][lr] = av.y;
        AsT[lc + 2][lr] = av.z; AsT[lc + 3][lr] = av.w;
        const float4 bw = *reinterpret_cast<const float4*>(&Wsel[orow * 512 + k0 + lc]);
        BsT[lc + 0][lr] = bw.x; BsT[lc + 1][lr] = bw.y;
        BsT[lc + 2][lr] = bw.z; BsT[lc + 3][lr] = bw.w;
        __syncthreads();
        #pragma unroll
        for (int kk = 0; kk < 16; ++kk) {
            const float4 a4 = *reinterpret_cast<const float4*>(&AsT[kk][ty * 4]);
            const float4 b4 = *reinterpret_cast<const float4*>(&BsT[kk][tx * 4]);
            const float ar[4] = {a4.x, a4.y, a4.z, a4.w};
            const float br[4] = {b4.x, b4.y, b4.z, b4.w};
            #pragma unroll
            for (int r = 0; r < 4; ++r)
                #pragma unroll
                for (int c = 0; c < 4; ++c) acc[r][c] = fmaf(ar[r], br[c], acc[r][c]);
        }
        __syncthreads();
    }

    #pragma unroll
    for (int c = 0; c < 4; ++c) {
        const int o = n0 + tx * 4 + c;
        const float* bsel = (o < 256) ? bq : (o < 512 ? bk : bv);
        const float bias = bsel[o & 255];
        #pragma unroll
        for (int r = 0; r < 4; ++r)
            sT[ty * 4 + r][tx * 4 + c] = acc[r][c] + bias;
    }
    __syncthreads();

    if (t < 128) {
        const int m = t >> 1, half = t & 1;
        const int row = m0 + m;
        const int b = row >> 9, tt = row & 511;
        const int which = n0 >> 8;
        const int h = ((n0 & 255) >> 5) + half;
        const int bh = b * Hq + h;

        float zv[32];
        float s2 = 0.f;
        #pragma unroll
        for (int k = 0; k < 32; ++k) { zv[k] = sT[m][half * 32 + k]; s2 = fmaf(zv[k], zv[k], s2); }
        const float rr = __builtin_amdgcn_sqrtf(s2);
        const float rs = fminf(fmaxf(rr, 1e-12f), 18.0f);
        const float e  = __expf(rs);
        const float ei = __builtin_amdgcn_rcpf(e);
        const float ch = 0.5f * (e + ei);
        float sc = 0.5f * (e - ei) / rs;
        if (rs < 1e-3f) sc = fmaf(rs * rs, 1.0f / 6.0f, 1.0f);
        float y0 = ch;
        float ys[32];
        float mink = -y0 * y0;
        #pragma unroll
        for (int k = 0; k < 32; ++k) { ys[k] = sc * zv[k]; mink = fmaf(ys[k], ys[k], mink); }
        const float inv = __builtin_amdgcn_rsqf(fmaxf(fabsf(mink), 1e-15f));
        y0 = fabsf(y0 * inv);

        if (which == 0) {
            float* qp = Q + (bh * Tq + tt) * QS;
            #pragma unroll
            for (int k = 0; k < 32; ++k) qp[k] = ys[k] * inv;
            qp[32] = y0;
        } else {
            float* p = ((which == 1) ? K : V) + bh * 33 * Tq + tt;
            p[0] = y0;
            #pragma unroll
            for (int k = 0; k < 32; ++k) p[(k + 1) * Tq] = ys[k] * inv;
        }
    }
}

// ---------------- Kernel 2: attention + Karcher step + origin log ----------
// 256 threads, 8 rows/block, 2 columns/thread, grid (64, 16).
__global__ __launch_bounds__(256) void attn_kernel(
    const float* __restrict__ Q, const float* __restrict__ K,
    const float* __restrict__ V, float* __restrict__ Ztan)
{
    __shared__ float sQ[8][36];       // [0..31]=spatial, [32]=time, 33-35 pad
    __shared__ float sBig[8 * 512];   // p matrix; P4 partials alias front
    __shared__ float sSe[8][4];       // per-wave sum_e partials
    __shared__ float sSa[8][4];       // per-wave sum_(p*al) partials
    __shared__ float sW[8][33];

    float (*sP)[512] = reinterpret_cast<float(*)[512]>(sBig);
    float (*part)[8][36] = reinterpret_cast<float(*)[8][36]>(sBig); // [g][sub][36]

    const int bh = blockIdx.y;
    const int i0 = blockIdx.x * 8;
    const int t  = threadIdx.x;       // 0..255
    const int lane = t & 63, wv = t >> 6;

    const float* Qb = Q + (bh * Tq + i0) * QS;
    const float* Kb = K + bh * 33 * Tq;
    const float* Vb = V + bh * 33 * Tq;

    // R6 fix: 288 floats, 256 threads -> strided loop (R5 dropped 32 tail)
    for (int idx = t; idx < 8 * QS; idx += 256)
        sQ[idx / QS][idx % QS] = Qb[idx];
    __syncthreads();

    // ---- P1: p = exp(-d^2)*dd into LDS; row sums of e and p*al in regs ----
    float se[8], sa[8];
    #pragma unroll
    for (int i = 0; i < 8; ++i) { se[i] = 0.f; sa[i] = 0.f; }

    #pragma unroll 1
    for (int cc = 0; cc < 2; ++cc) {
        const int j = (cc << 8) + t;
        float aK[8], aV[8];
        #pragma unroll
        for (int i = 0; i < 8; ++i) { aK[i] = 0.f; aV[i] = 0.f; }
        #pragma unroll 2
        for (int ch = 0; ch < 4; ++ch) {
            float ks[8], vs[8];
            #pragma unroll
            for (int k = 0; k < 8; ++k) {
                ks[k] = Kb[(ch * 8 + k + 1) * Tq + j];
                vs[k] = Vb[(ch * 8 + k + 1) * Tq + j];
            }
            #pragma unroll
            for (int i = 0; i < 8; ++i) {
                const float4 qa = *reinterpret_cast<const float4*>(&sQ[i][ch * 8]);
                const float4 qb = *reinterpret_cast<const float4*>(&sQ[i][ch * 8 + 4]);
                float sK = aK[i], sV = aV[i];
                sK = fmaf(qa.x, ks[0], sK); sK = fmaf(qa.y, ks[1], sK);
                sK = fmaf(qa.z, ks[2], sK); sK = fmaf(qa.w, ks[3], sK);
                sK = fmaf(qb.x, ks[4], sK); sK = fmaf(qb.y, ks[5], sK);
                sK = fmaf(qb.z, ks[6], sK); sK = fmaf(qb.w, ks[7], sK);
                sV = fmaf(qa.x, vs[0], sV); sV = fmaf(qa.y, vs[1], sV);
                sV = fmaf(qa.z, vs[2], sV); sV = fmaf(qa.w, vs[3], sV);
                sV = fmaf(qb.x, vs[4], sV); sV = fmaf(qb.y, vs[5], sV);
                sV = fmaf(qb.z, vs[6], sV); sV = fmaf(qb.w, vs[7], sV);
                aK[i] = sK; aV[i] = sV;
            }
        }
        const float k0v = Kb[j], v0v = Vb[j];
        #pragma unroll
        for (int i = 0; i < 8; ++i) {
            const float q0 = sQ[i][32];
            const float ipK = fmaf(q0, k0v, -aK[i]);
            const float d   = facosh(fmaxf(ipK, 1.0f + EPSF));
            const float al  = fmaxf(fmaf(q0, v0v, -aV[i]), 1.0f + EPSF);
            const float dd  = facosh(al);
            const float e   = __expf(-d * d);
            const float p   = e * dd;
            sP[i][j] = p;
            se[i] += e;
            sa[i]  = fmaf(p, al, sa[i]);
        }
    }
    #pragma unroll
    for (int i = 0; i < 8; ++i) {
        float a = se[i], b = sa[i];
        #pragma unroll
        for (int off = 32; off > 0; off >>= 1) {
            a += __shfl_xor(a, off, 64);
            b += __shfl_xor(b, off, 64);
        }
        if (lane == 0) { sSe[i][wv] = a; sSa[i][wv] = b; }
    }
    __syncthreads();

    // ---- P4: Wraw[i][a] = sum_j p_ij * V[a][j] ----------------------------
    // 8 groups of 32 lanes: g = ag*2 + rg; rows rg*4..+3, a = ag*8..+8 (9 wide).
    {
        const int jl = t & 31, g = t >> 5;
        const int rg = g & 1, ag = g >> 1;
        const int abase = ag * 8;         // 0,8,16,24; +8 = 32 max, in range
        const int ibase = rg * 4;
        float acc[4][9];
        #pragma unroll
        for (int il = 0; il < 4; ++il)
            #pragma unroll
            for (int al = 0; al < 9; ++al) acc[il][al] = 0.f;

        #pragma unroll 1
        for (int it = 0; it < 8; ++it) {
            const int jb = it * 64 + jl * 2;
            float2 v2[9];
            #pragma unroll
            for (int al = 0; al < 9; ++al)
                v2[al] = *reinterpret_cast<const float2*>(&Vb[(abase + al) * Tq + jb]);
            #pragma unroll
            for (int il = 0; il < 4; ++il) {
                const float2 w2 = *reinterpret_cast<const float2*>(&sP[ibase + il][jb]);
                #pragma unroll
                for (int al = 0; al < 9; ++al)
                    acc[il][al] = fmaf(w2.y, v2[al].y, fmaf(w2.x, v2[al].x, acc[il][al]));
            }
        }
        #pragma unroll
        for (int il = 0; il < 4; ++il)
            #pragma unroll
            for (int al = 0; al < 9; ++al) {
                float v = acc[il][al];
                v += __shfl_xor(v, 1, 64);
                v += __shfl_xor(v, 2, 64);
                acc[il][al] = v;
            }
        __syncthreads();   // all sP reads complete before part overwrites
        if ((jl & 3) == 0) {
            const int sub = jl >> 2;
            #pragma unroll
            for (int il = 0; il < 4; ++il)
                #pragma unroll
                for (int al = 0; al < 9; ++al)
                    part[g][sub][il * 9 + al] = acc[il][al];
        }
    }
    __syncthreads();

    // ---- stage 2: fold 8 partials per (i,a) -------------------------------
    for (int task = t; task < 8 * 33; task += 256) {
        const int i = task / 33, a = task - i * 33;
        int ag2 = a >> 3; if (ag2 > 3) ag2 = 3;
        const int al = a - ag2 * 8;
        const int g2 = ag2 * 2 + (i >> 2);
        const int idx = (i & 3) * 9 + al;
        float s = 0.f;
        #pragma unroll
        for (int sub = 0; sub < 8; ++sub) s += part[g2][sub][idx];
        sW[i][a] = s;
    }
    __syncthreads();

    // ---- P5: normalize + degenerate exp_map + project + origin log --------
    if (t < 8) {
        const int i = t;
        const float seT = sSe[i][0] + sSe[i][1] + sSe[i][2] + sSe[i][3];
        const float saT = sSa[i][0] + sSa[i][1] + sSa[i][2] + sSa[i][3];
        const float sInv = __builtin_amdgcn_rcpf(seT);
        const float cs = CINV * sInv;     // C * (1/sum_e)
        const float q0 = sQ[i][32];
        const float y0 = fmaf(cs, fmaf(saT, q0, sW[i][0]), q0);
        float mink = -y0 * y0;
        float yv[32];
        #pragma unroll
        for (int a = 1; a < 33; ++a) {
            const float qa = sQ[i][a - 1];
            const float ya = fmaf(cs, fmaf(saT, qa, sW[i][a]), qa);
            yv[a - 1] = ya;
            mink = fmaf(ya, ya, mink);
        }
        const float inv = __builtin_amdgcn_rsqf(fmaxf(fabsf(mink), 1e-15f));
        const float Y0 = fabsf(y0 * inv);
        const float dist0 = facosh(fmaxf(Y0, 1.0f + EPSF));
        const float coef = dist0 * CINV;
        const int b = bh >> 3, h = bh & 7;
        float* zp = Ztan + ((b * Tq + (i0 + i)) * 264) + h * 33;
        zp[0] = coef * (2.0f * Y0);
        #pragma unroll
        for (int a = 1; a < 33; ++a) zp[a] = coef * (yv[a - 1] * inv);
    }
}

// ---------------- Kernel 3: Z = Ztan(1024x264) @ Wo^T + bo (as R3) ---------
__global__ __launch_bounds__(256) void out_gemm_kernel(
    const float* __restrict__ Ztan, const float* __restrict__ Wo,
    const float* __restrict__ bo, float* __restrict__ out)
{
    __shared__ float AsT[8][68];
    __shared__ float BsT[8][68];
    const int n0 = blockIdx.x * 64;
    const int m0 = blockIdx.y * 64;
    const int t  = threadIdx.x;
    const int tx = t & 15, ty = t >> 4;
    const int lr = t >> 2;
    const int lc = (t & 3) * 2;

    float acc[4][4];
    #pragma unroll
    for (int r = 0; r < 4; ++r)
        #pragma unroll
        for (int c = 0; c < 4; ++c) acc[r][c] = 0.f;

    for (int k0 = 0; k0 < 264; k0 += 8) {
        const float2 av = *reinterpret_cast<const float2*>(&Ztan[(m0 + lr) * 264 + k0 + lc]);
        AsT[lc][lr] = av.x; AsT[lc + 1][lr] = av.y;
        const float2 bw = *reinterpret_cast<const float2*>(&Wo[(n0 + lr) * 264 + k0 + lc]);
        BsT[lc][lr] = bw.x; BsT[lc + 1][lr] = bw.y;
        __syncthreads();
        #pragma unroll
        for (int kk = 0; kk < 8; ++kk) {
            const float4 a4 = *reinterpret_cast<const float4*>(&AsT[kk][ty * 4]);
            const float4 b4 = *reinterpret_cast<const float4*>(&BsT[kk][tx * 4]);
            const float ar[4] = {a4.x, a4.y, a4.z, a4.w};
            const float br[4] = {b4.x, b4.y, b4.z, b4.w};
            #pragma unroll
            for (int r = 0; r < 4; ++r)
                #pragma unroll
                for (int c = 0; c < 4; ++c) acc[r][c] = fmaf(ar[r], br[c], acc[r][c]);
        }
        __syncthreads();
    }
    #pragma unroll
    for (int c = 0; c < 4; ++c) {
        const int o = n0 + tx * 4 + c;
        const float bias = bo[o];
        #pragma unroll
        for (int r = 0; r < 4; ++r)
            out[(m0 + ty * 4 + r) * 512 + o] = acc[r][c] + bias;
    }
}

} // namespace

// ---------------------------------------------------------------------------
extern "C" void kernel_launch(void* const* d_in, const int* in_sizes, int n_in,
                              void* d_out, int out_size, void* d_ws, size_t ws_size,
                              hipStream_t stream)
{
    const float* x  = (const float*)d_in[0];
    const float* Wq = (const float*)d_in[1];
    const float* bq = (const float*)d_in[2];
    const float* Wk = (const float*)d_in[3];
    const float* bk = (const float*)d_in[4];
    const float* Wv = (const float*)d_in[5];
    const float* bv = (const float*)d_in[6];
    const float* Wo = (const float*)d_in[7];
    const float* bo = (const float*)d_in[8];
    float* out = (float*)d_out;

    float* ws   = (float*)d_ws;
    float* Qw   = ws;                        // 16*512*36 = 294912
    float* Kw   = ws + 294912;               // 16*33*512 + pad = 272384
    float* Vw   = ws + 294912 + 272384;
    float* Zt   = ws + 294912 + 2 * 272384;  // 1024*264 = 270336

    gemm_qkv_fl_kernel<<<dim3(12, 16), 256, 0, stream>>>(x, Wq, bq, Wk, bk, Wv, bv,
                                                         Qw, Kw, Vw);
    attn_kernel<<<dim3(64, 16), 256, 0, stream>>>(Qw, Kw, Vw, Zt);
    out_gemm_kernel<<<dim3(8, 16), 256, 0, stream>>>(Zt, Wo, bo, out);
}